// Round 1
// baseline (943.970 us; speedup 1.0000x reference)
//
#include <hip/hip_runtime.h>
#include <hip/hip_bf16.h>
#include <cstdint>

#define T_TOK 1024
#define HID   2048
#define INTER 1024
#define NEXP  32
#define NTOT  40
#define RSF   1.0f

typedef short bf16x8 __attribute__((ext_vector_type(8)));
typedef float f32x4  __attribute__((ext_vector_type(4)));

__device__ inline short f2bf(float f) {
    unsigned x = __builtin_bit_cast(unsigned, f);
    x += 0x7fffu + ((x >> 16) & 1u);           // round-to-nearest-even
    return (short)(x >> 16);
}

// ---------------- Kernel 1: router (fp32 exact) ----------------
__global__ __launch_bounds__(256) void k_router(
    const float* __restrict__ hs, const float* __restrict__ rw,
    const float* __restrict__ cb, int* __restrict__ topk_ids,
    float* __restrict__ topk_w, float* __restrict__ zero_w,
    int* __restrict__ counts)
{
    int t = blockIdx.x;
    __shared__ float hrow[HID];
    __shared__ float sc[NTOT];
    const float* h = hs + (size_t)t * HID;
    for (int i = threadIdx.x; i < HID / 4; i += 256)
        ((float4*)hrow)[i] = ((const float4*)h)[i];
    __syncthreads();
    int wid = threadIdx.x >> 6, lane = threadIdx.x & 63;
    for (int e = wid; e < NTOT; e += 4) {
        const float* w = rw + (size_t)e * HID;
        float p = 0.f;
        for (int k = lane; k < HID; k += 64) p += hrow[k] * w[k];
        for (int s = 32; s; s >>= 1) p += __shfl_down(p, s, 64);
        if (lane == 0) sc[e] = 1.f / (1.f + expf(-p));
    }
    __syncthreads();
    if (threadIdx.x == 0) {
        float key[NTOT];
        for (int e = 0; e < NTOT; e++) key[e] = sc[e] + cb[e];
        float zw = 0.f;
        for (int k = 0; k < 4; k++) {
            int best = 0; float bv = key[0];
            for (int e = 1; e < NTOT; e++)
                if (key[e] > bv) { bv = key[e]; best = e; }
            key[best] = -1e30f;
            topk_ids[t * 4 + k] = best;
            float wv = sc[best];
            topk_w[t * 4 + k] = wv;
            if (best >= NEXP) zw += wv;
            else atomicAdd(&counts[best], 1);
        }
        zero_w[t] = zw * RSF;
    }
}

// ---------------- Kernel 2: prefix (pad to 128) ----------------
__global__ void k_prefix(const int* __restrict__ counts, int* __restrict__ offsets)
{
    if (threadIdx.x == 0 && blockIdx.x == 0) {
        int acc = 0;
        for (int e = 0; e < NEXP; e++) {
            offsets[e] = acc;
            acc += (counts[e] + 127) & ~127;
        }
        offsets[NEXP] = acc;
    }
}

// ---------------- Kernel 3: scatter into buckets ----------------
__global__ void k_scatter(const int* __restrict__ topk_ids, const float* __restrict__ topk_w,
                          const int* __restrict__ offsets, int* __restrict__ cnt2,
                          int* __restrict__ btok, float* __restrict__ bw)
{
    int t = blockIdx.x * 256 + threadIdx.x;
    if (t >= T_TOK) return;
    for (int k = 0; k < 4; k++) {
        int e = topk_ids[t * 4 + k];
        if (e < NEXP) {
            int pos  = atomicAdd(&cnt2[e], 1);
            int slot = offsets[e] + pos;
            btok[slot] = t;
            bw[slot]   = topk_w[t * 4 + k];
        }
    }
}

// ---------------- Kernel 4: grouped GEMM1 + silu -> Hbuf (bf16) ----------------
// grid: x = I/64 (16), y = m-tile (8), z = expert (32); 256 thr; C tile 128x128 = [gate64|up64]
__global__ __launch_bounds__(256, 2) void k_ffn1(
    const float* __restrict__ hs, const float* __restrict__ w1g, const float* __restrict__ w1u,
    const int* __restrict__ counts, const int* __restrict__ offsets,
    const int* __restrict__ btok, unsigned short* __restrict__ Hbuf)
{
    int e = blockIdx.z, mt = blockIdx.y, it = blockIdx.x;
    int ne = counts[e];
    if (mt * 128 >= ne) return;
    int base  = offsets[e] + mt * 128;
    int valid = ne - mt * 128; if (valid > 128) valid = 128;

    __shared__ __align__(16) char smem[65536];
    short* At  = (short*)smem;              // [128][32] bf16, 8 KB
    short* Bt  = (short*)(smem + 8192);     // [128][32] bf16, 8 KB
    int*   tok = (int*)(smem + 16384);      // [128]
    float* Cb  = (float*)smem;              // epilogue overlay [128][128] fp32

    int tid = threadIdx.x;
    if (tid < 128) tok[tid] = (tid < valid) ? btok[base + tid] : btok[base];
    __syncthreads();

    const float* wg = w1g + (size_t)e * INTER * HID + (size_t)(it * 64) * HID;
    const float* wu = w1u + (size_t)e * INTER * HID + (size_t)(it * 64) * HID;

    const float* aptr[4]; short* adst[4];
    const float* bptr[4]; short* bdst[4];
#pragma unroll
    for (int u = 0; u < 4; u++) {
        int idx = tid + u * 256;
        int r = idx >> 3, seg = idx & 7;
        aptr[u] = hs + (size_t)tok[r] * HID + seg * 4;
        adst[u] = At + r * 32 + seg * 4;
        bptr[u] = (r < 64 ? wg + (size_t)r * HID : wu + (size_t)(r - 64) * HID) + seg * 4;
        bdst[u] = Bt + r * 32 + seg * 4;
    }

    int wid = tid >> 6, lane = tid & 63;
    int wrow = (wid >> 1) * 64, wcol = (wid & 1) * 64;
    int lrow = lane & 15, quad = lane >> 4;
    f32x4 acc[4][4];
#pragma unroll
    for (int mi = 0; mi < 4; mi++)
#pragma unroll
        for (int ni = 0; ni < 4; ni++) acc[mi][ni] = 0.f;

    for (int k0 = 0; k0 < HID; k0 += 32) {
#pragma unroll
        for (int u = 0; u < 4; u++) {
            float4 va = *(const float4*)(aptr[u] + k0);
            float4 vb = *(const float4*)(bptr[u] + k0);
            *(short4*)adst[u] = make_short4(f2bf(va.x), f2bf(va.y), f2bf(va.z), f2bf(va.w));
            *(short4*)bdst[u] = make_short4(f2bf(vb.x), f2bf(vb.y), f2bf(vb.z), f2bf(vb.w));
        }
        __syncthreads();
        bf16x8 af[4], bfr[4];
#pragma unroll
        for (int mi = 0; mi < 4; mi++)
            af[mi] = *(bf16x8*)(At + (wrow + mi * 16 + lrow) * 32 + quad * 8);
#pragma unroll
        for (int ni = 0; ni < 4; ni++)
            bfr[ni] = *(bf16x8*)(Bt + (wcol + ni * 16 + lrow) * 32 + quad * 8);
#pragma unroll
        for (int mi = 0; mi < 4; mi++)
#pragma unroll
            for (int ni = 0; ni < 4; ni++)
                acc[mi][ni] = __builtin_amdgcn_mfma_f32_16x16x32_bf16(af[mi], bfr[ni], acc[mi][ni], 0, 0, 0);
        __syncthreads();
    }

    // epilogue: C -> LDS, fuse silu(g)*u, write bf16 Hbuf
#pragma unroll
    for (int mi = 0; mi < 4; mi++)
#pragma unroll
        for (int ni = 0; ni < 4; ni++)
#pragma unroll
            for (int r = 0; r < 4; r++)
                Cb[(wrow + mi * 16 + quad * 4 + r) * 128 + (wcol + ni * 16 + lrow)] = acc[mi][ni][r];
    __syncthreads();
    for (int idx = tid; idx < 128 * 64; idx += 256) {
        int m = idx >> 6, c = idx & 63;
        float g = Cb[m * 128 + c];
        float u = Cb[m * 128 + 64 + c];
        float h = g / (1.f + __expf(-g)) * u;
        Hbuf[(size_t)(base + m) * INTER + it * 64 + c] = (unsigned short)f2bf(h);
    }
}

// ---------------- Kernel 5: out = hidden * zero_weight ----------------
__global__ void k_init_out(const float* __restrict__ hs, const float* __restrict__ zw,
                           float* __restrict__ out)
{
    int idx = blockIdx.x * 256 + threadIdx.x;   // float4 index
    int t = idx >> 9;                           // HID/4 = 512 per row
    float4 v = ((const float4*)hs)[idx];
    float s = zw[t];
    v.x *= s; v.y *= s; v.z *= s; v.w *= s;
    ((float4*)out)[idx] = v;
}

// ---------------- Kernel 6: grouped GEMM2, weighted atomic accumulate ----------------
// grid: x = H/128 (16), y = m-tile (8), z = expert (32); 256 thr; C tile 128x128
__global__ __launch_bounds__(256, 2) void k_ffn2(
    const unsigned short* __restrict__ Hbuf, const float* __restrict__ w2,
    const int* __restrict__ counts, const int* __restrict__ offsets,
    const int* __restrict__ btok, const float* __restrict__ bw,
    float* __restrict__ out)
{
    int e = blockIdx.z, mt = blockIdx.y, ht = blockIdx.x;
    int ne = counts[e];
    if (mt * 128 >= ne) return;
    int base  = offsets[e] + mt * 128;
    int valid = ne - mt * 128; if (valid > 128) valid = 128;

    __shared__ __align__(16) short At[128 * 32];
    __shared__ __align__(16) short Bt[128 * 32];
    __shared__ int   tok[128];
    __shared__ float wgt[128];

    int tid = threadIdx.x;
    if (tid < 128) {
        tok[tid] = (tid < valid) ? btok[base + tid] : btok[base];
        wgt[tid] = (tid < valid) ? bw[base + tid] : 0.f;
    }
    __syncthreads();

    const float* w2e = w2 + (size_t)e * HID * INTER;
    const unsigned short* asrc[2]; short* adst[2];
#pragma unroll
    for (int u = 0; u < 2; u++) {
        int idx = tid + u * 256;
        int r = idx >> 2, seg = idx & 3;
        asrc[u] = Hbuf + (size_t)(base + r) * INTER + seg * 8;
        adst[u] = At + r * 32 + seg * 8;
    }
    const float* bptr[4]; short* bdst[4];
#pragma unroll
    for (int u = 0; u < 4; u++) {
        int idx = tid + u * 256;
        int r = idx >> 3, seg = idx & 7;
        bptr[u] = w2e + (size_t)(ht * 128 + r) * INTER + seg * 4;
        bdst[u] = Bt + r * 32 + seg * 4;
    }

    int wid = tid >> 6, lane = tid & 63;
    int wrow = (wid >> 1) * 64, wcol = (wid & 1) * 64;
    int lrow = lane & 15, quad = lane >> 4;
    f32x4 acc[4][4];
#pragma unroll
    for (int mi = 0; mi < 4; mi++)
#pragma unroll
        for (int ni = 0; ni < 4; ni++) acc[mi][ni] = 0.f;

    for (int k0 = 0; k0 < INTER; k0 += 32) {
#pragma unroll
        for (int u = 0; u < 2; u++) {
            int4 v = *(const int4*)(asrc[u] + k0);
            *(int4*)adst[u] = v;
        }
#pragma unroll
        for (int u = 0; u < 4; u++) {
            float4 vb = *(const float4*)(bptr[u] + k0);
            *(short4*)bdst[u] = make_short4(f2bf(vb.x), f2bf(vb.y), f2bf(vb.z), f2bf(vb.w));
        }
        __syncthreads();
        bf16x8 af[4], bfr[4];
#pragma unroll
        for (int mi = 0; mi < 4; mi++)
            af[mi] = *(bf16x8*)(At + (wrow + mi * 16 + lrow) * 32 + quad * 8);
#pragma unroll
        for (int ni = 0; ni < 4; ni++)
            bfr[ni] = *(bf16x8*)(Bt + (wcol + ni * 16 + lrow) * 32 + quad * 8);
#pragma unroll
        for (int mi = 0; mi < 4; mi++)
#pragma unroll
            for (int ni = 0; ni < 4; ni++)
                acc[mi][ni] = __builtin_amdgcn_mfma_f32_16x16x32_bf16(af[mi], bfr[ni], acc[mi][ni], 0, 0, 0);
        __syncthreads();
    }

    // epilogue: weighted atomic accumulate into out (fp32)
#pragma unroll
    for (int mi = 0; mi < 4; mi++) {
#pragma unroll
        for (int r = 0; r < 4; r++) {
            int m = wrow + mi * 16 + quad * 4 + r;
            if (m < valid) {
                int   t = tok[m];
                float w = wgt[m] * RSF;
#pragma unroll
                for (int ni = 0; ni < 4; ni++) {
                    int col = ht * 128 + wcol + ni * 16 + lrow;
                    atomicAdd(&out[(size_t)t * HID + col], acc[mi][ni][r] * w);
                }
            }
        }
    }
}

extern "C" void kernel_launch(void* const* d_in, const int* in_sizes, int n_in,
                              void* d_out, int out_size, void* d_ws, size_t ws_size,
                              hipStream_t stream)
{
    const float* hs  = (const float*)d_in[0];
    const float* rw  = (const float*)d_in[1];
    const float* cb  = (const float*)d_in[2];
    const float* w1g = (const float*)d_in[3];
    const float* w1u = (const float*)d_in[4];
    const float* w2  = (const float*)d_in[5];
    float* out = (float*)d_out;

    char* ws = (char*)d_ws;
    int*   counts   = (int*)(ws + 0);        // 32
    int*   cnt2     = (int*)(ws + 128);      // 32
    int*   offsets  = (int*)(ws + 256);      // 33
    int*   topk_ids = (int*)(ws + 4096);     // 1024*4
    float* topk_w   = (float*)(ws + 20480);  // 1024*4
    float* zero_w   = (float*)(ws + 36864);  // 1024
    int*   btok     = (int*)(ws + 40960);    // 8192
    float* bww      = (float*)(ws + 73728);  // 8192
    unsigned short* Hbuf = (unsigned short*)(ws + 131072); // 8192*1024 bf16 = 16 MB

    hipMemsetAsync(d_ws, 0, 4096, stream);   // counts/cnt2/offsets

    k_router<<<T_TOK, 256, 0, stream>>>(hs, rw, cb, topk_ids, topk_w, zero_w, counts);
    k_prefix<<<1, 64, 0, stream>>>(counts, offsets);
    k_scatter<<<4, 256, 0, stream>>>(topk_ids, topk_w, offsets, cnt2, btok, bww);
    k_ffn1<<<dim3(16, 8, 32), 256, 0, stream>>>(hs, w1g, w1u, counts, offsets, btok, Hbuf);
    k_init_out<<<(T_TOK * HID / 4) / 256, 256, 0, stream>>>(hs, zero_w, out);
    k_ffn2<<<dim3(16, 8, 32), 256, 0, stream>>>(Hbuf, w2, counts, offsets, btok, bww, out);
}